// Round 1
// baseline (13916.966 us; speedup 1.0000x reference)
//
#include <hip/hip_runtime.h>
#include <stdint.h>
#include <math.h>

// Bayesian STDP persistent-scan kernel.
// T=1000 sequential steps; G=32 workgroups each own NO=4 output neurons.
// One device-wide barrier per step; softmax merged via online (max,sum) partials.
// psp trace: triple-buffered in d_ws (shard-updated pre-barrier).
// All state fp32; W/b tile + u live in LDS per WG.

#define TSTEPS 1000
#define BB     64
#define NINF   512
#define NOUTT  128
#define NG     32          // workgroups
#define NO     4           // outputs per WG = NOUTT/NG
#define NTHR   1024
#define PSPD   0.9f
#define VD     0.9f
#define LRC    1e-3f

#define PSPN      (BB*NINF)                 // 32768 floats per psp buffer
#define STATS_OFF (3*PSPN)                  // [2][NG][BB][2] floats
#define CTRL_OFF  (STATS_OFF + 2*NG*BB*2)   // ints: arrv[NG], cnt

__global__ __launch_bounds__(NTHR, 1)
void bstdp_kernel(const float* __restrict__ spikes,   // [T][B][NIN]
                  const float* __restrict__ weight,   // [NOUT][NIN]
                  const float* __restrict__ bias,     // [NOUT]
                  float* __restrict__ out,            // [T][B][NOUT] ++ [B][NOUT]
                  float* __restrict__ ws)
{
  const int g   = blockIdx.x;
  const int tid = threadIdx.x;

  float* pspb  = ws;                 // 3 * PSPN
  float* stats = ws + STATS_OFF;     // 2 * NG * BB * 2
  int*   ctrl  = (int*)(ws + CTRL_OFF);
  int*   arrv  = ctrl;               // [NG] slot barrier (poison-safe: 0xAA.. < 1)
  int*   cnt   = ctrl + NG;          // counter barrier

  __shared__ __align__(16) float Wt[NO*NINF];      // 8 KB   W tile (state)
  __shared__ __align__(16) float part[4*NO*NINF];  // 32 KB  post_pre partials
  __shared__ __align__(16) float uS[NO*BB];        // membrane state [o][b]
  __shared__ __align__(16) float zS[NO*BB];        // z_out tile [o][b]
  __shared__ float pmS[NO];
  __shared__ float btS[NO];

  // counter init must precede slot barrier arrivals (ordered by threadfence below)
  if (g == 0 && tid == 0) atomicExch(cnt, 0);

  // ---- prologue: load W/b tile, zero u, psp(0) shard = spikes(0) ----
  Wt[tid]        = weight[g*(NO*NINF) + tid];
  Wt[tid + NTHR] = weight[g*(NO*NINF) + tid + NTHR];
  if (tid < NO)     btS[tid] = bias[g*NO + tid];
  if (tid < NO*BB)  uS[tid] = 0.0f;
  {
    int idx = g*(PSPN/NG) + tid;               // 1024-float shard, 1/thread
    pspb[idx] = spikes[idx];                   // psp(0) = 0.9*0 + s(0)
  }

  // ---- barrier #0: slot-array (safe vs 0xAA poison) ----
  __syncthreads();
  if (tid == 0) { __threadfence(); atomicExch(&arrv[g], 1); }
  if (tid < NG) {
    while (__hip_atomic_load(&arrv[tid], __ATOMIC_RELAXED, __HIP_MEMORY_SCOPE_AGENT) < 1)
      __builtin_amdgcn_s_sleep(2);
  }
  __syncthreads();
  if (tid == 0) __threadfence();
  __syncthreads();

  const int bp = tid >> 5;      // 0..31 : batch row pair (bp, bp+32)
  const int cc = tid & 31;      // 0..31 : 16-float i-chunk
  const int q4 = tid & 3;       // local o (when tid<256)
  const int b4 = tid >> 2;      // batch row (when tid<256)

  for (int t = 0; t < TSTEPS; ++t) {
    const int p  = t % 3;
    const int pn = (t+1) % 3;
    const int sb = t & 1;
    const float* pspP = pspb + p*PSPN;

    // ---------- phase 1: z_in = psp @ W^T + b ; u = 0.9u + z_in ; local stats ----------
    {
      float a0[NO] = {0.f,0.f,0.f,0.f};
      float a1[NO] = {0.f,0.f,0.f,0.f};
      const float* r0 = pspP + bp*NINF + cc*16;
      const float* r1 = pspP + (bp+32)*NINF + cc*16;
      #pragma unroll
      for (int m = 0; m < 4; ++m) {
        float4 p0 = *(const float4*)(r0 + m*4);
        float4 p1 = *(const float4*)(r1 + m*4);
        #pragma unroll
        for (int o = 0; o < NO; ++o) {
          float4 w4 = *(const float4*)(&Wt[o*NINF + cc*16 + m*4]);
          a0[o] += p0.x*w4.x + p0.y*w4.y + p0.z*w4.z + p0.w*w4.w;
          a1[o] += p1.x*w4.x + p1.y*w4.y + p1.z*w4.z + p1.w*w4.w;
        }
      }
      #pragma unroll
      for (int m = 1; m < 32; m <<= 1) {
        #pragma unroll
        for (int o = 0; o < NO; ++o) {
          a0[o] += __shfl_xor(a0[o], m);
          a1[o] += __shfl_xor(a1[o], m);
        }
      }
      if (cc == 0) {
        #pragma unroll
        for (int o = 0; o < NO; ++o) {
          uS[o*BB + bp]      = VD*uS[o*BB + bp]      + a0[o] + btS[o];
          uS[o*BB + bp + 32] = VD*uS[o*BB + bp + 32] + a1[o] + btS[o];
        }
      }
    }
    __syncthreads();
    // local softmax stats over this WG's 4 neurons
    if (tid < BB) {
      float u0 = uS[0*BB+tid], u1 = uS[1*BB+tid], u2 = uS[2*BB+tid], u3 = uS[3*BB+tid];
      float mx = fmaxf(fmaxf(u0,u1), fmaxf(u2,u3));
      float ssum = expf(u0-mx)+expf(u1-mx)+expf(u2-mx)+expf(u3-mx);
      *(float2*)(stats + ((size_t)(sb*NG + g)*BB + tid)*2) = make_float2(mx, ssum);
    }
    // ---------- phase 2: psp shard -> step t+1 (triple buffer) ----------
    if (t+1 < TSTEPS && tid < 256) {
      int idx = g*(PSPN/NG) + tid*4;
      float4 pv = *(const float4*)(pspP + idx);
      float4 sv = *(const float4*)(spikes + (size_t)(t+1)*PSPN + idx);
      float4 nv;
      nv.x = PSPD*pv.x + sv.x;  nv.y = PSPD*pv.y + sv.y;
      nv.z = PSPD*pv.z + sv.z;  nv.w = PSPD*pv.w + sv.w;
      *(float4*)(pspb + pn*PSPN + idx) = nv;
    }
    // ---------- phase 3: device-wide barrier (counter) ----------
    __syncthreads();
    if (tid == 0) {
      __threadfence();                       // release: flush stats + psp shard
      atomicAdd(cnt, 1);
      const int target = NG*(t+1);
      while (__hip_atomic_load(cnt, __ATOMIC_RELAXED, __HIP_MEMORY_SCOPE_AGENT) < target)
        __builtin_amdgcn_s_sleep(2);
      __threadfence();                       // acquire: invalidate L1/L2
    }
    __syncthreads();

    // ---------- phase 4: merge stats (online softmax), z_out ----------
    if (tid < 256) {
      float M = -1e30f, S = 0.f;
      #pragma unroll
      for (int k = 0; k < 8; ++k) {
        int gg = q4*8 + k;
        float2 msv = *(const float2*)(stats + ((size_t)(sb*NG + gg)*BB + b4)*2);
        float Mn = fmaxf(M, msv.x);
        S = S*expf(M - Mn) + msv.y*expf(msv.x - Mn);
        M = Mn;
      }
      #pragma unroll
      for (int m = 1; m < 4; m <<= 1) {
        float Mo = __shfl_xor(M, m);
        float So = __shfl_xor(S, m);
        float Mn = fmaxf(M, Mo);
        S = S*expf(M - Mn) + So*expf(Mo - Mn);
        M = Mn;
      }
      float z = expf(uS[q4*BB + b4] - M) / S;
      zS[q4*BB + b4] = z;
      out[(size_t)t*(BB*NOUTT) + (size_t)b4*NOUTT + g*NO + q4] = z;
    }
    __syncthreads();
    // ---------- phase 5a: post_mean (batch mean of z_out per neuron) ----------
    if (tid < 256) {
      int w = tid >> 6, lane = tid & 63;
      float v = zS[w*BB + lane];
      #pragma unroll
      for (int m = 1; m < 64; m <<= 1) v += __shfl_xor(v, m);
      if (lane == 0) pmS[w] = v * (1.0f/BB);
    }
    __syncthreads();
    // ---------- phase 5b: post_pre partials: part[bh][o][i] = sum_{b in bh} z[b,o]*psp[b,i] ----------
    {
      const int bh = tid >> 8;          // 0..3 (16 batch rows each)
      const int i0 = (tid & 255) * 2;   // i-pair
      float a[NO][2] = {};
      #pragma unroll
      for (int bo = 0; bo < 16; ++bo) {
        int b = bh*16 + bo;
        float2 pv = *(const float2*)(pspP + b*NINF + i0);
        #pragma unroll
        for (int o = 0; o < NO; ++o) {
          float z = zS[o*BB + b];
          a[o][0] += z*pv.x;
          a[o][1] += z*pv.y;
        }
      }
      #pragma unroll
      for (int o = 0; o < NO; ++o) {
        part[(bh*NO + o)*NINF + i0]     = a[o][0];
        part[(bh*NO + o)*NINF + i0 + 1] = a[o][1];
      }
    }
    __syncthreads();
    // ---------- phase 5c: W,b update (Nessler rule) ----------
    {
      #pragma unroll
      for (int r = 0; r < 2; ++r) {
        int idx = tid*2 + r;            // 0..2047 == o*512+i
        int o = idx >> 9;
        float pp = (part[idx] + part[idx+2048] + part[idx+4096] + part[idx+6144]) * (1.0f/BB);
        float wv = Wt[idx];
        Wt[idx] = wv + LRC*(expf(-wv)*pp - pmS[o]);
      }
      if (tid < NO) {
        float bv = btS[tid];
        btS[tid] = bv + LRC*(expf(-bv) - 1.0f)*pmS[tid];
      }
    }
    __syncthreads();
  }

  // ---- epilogue: u_final ----
  if (tid < 256) {
    out[(size_t)TSTEPS*(BB*NOUTT) + (size_t)b4*NOUTT + g*NO + q4] = uS[q4*BB + b4];
  }
}

extern "C" void kernel_launch(void* const* d_in, const int* in_sizes, int n_in,
                              void* d_out, int out_size, void* d_ws, size_t ws_size,
                              hipStream_t stream) {
  const float* spikes = (const float*)d_in[0];   // [1000,64,512] fp32
  const float* weight = (const float*)d_in[1];   // [128,512] fp32
  const float* bias   = (const float*)d_in[2];   // [128] fp32
  float* out = (float*)d_out;                    // [1000*64*128] ++ [64*128]
  float* ws  = (float*)d_ws;                     // needs ~426 KB

  bstdp_kernel<<<dim3(NG), dim3(NTHR), 0, stream>>>(spikes, weight, bias, out, ws);
}